// Round 4
// baseline (1144.207 us; speedup 1.0000x reference)
//
#include <hip/hip_runtime.h>

#define HDIM 16
#define BSHIFT 9                  // 512 nodes per bucket
#define BNODES (1 << BSHIFT)
#define NBMAX 256                 // max buckets supported (n=100K -> 196)
#define CAP 32                    // staged entries per bucket in bin_kernel
#define SPLIT 4                   // blocks per bucket in agg_kernel

// ---------------------------------------------------------------------------
// per-node degree (global atomics) + per-bucket histogram (LDS -> global)
// ---------------------------------------------------------------------------
__global__ void hist_count_kernel(const int* __restrict__ dst, int* __restrict__ cnt,
                                  int* __restrict__ hist, int E, int nb) {
    __shared__ int lh[NBMAX];
    for (int t = threadIdx.x; t < nb; t += blockDim.x) lh[t] = 0;
    __syncthreads();
    int i = blockIdx.x * blockDim.x + threadIdx.x;
    int stride = gridDim.x * blockDim.x;
    for (; i < E; i += stride) {
        int d = dst[i];
        atomicAdd(&cnt[d], 1);              // fire-and-forget
        atomicAdd(&lh[d >> BSHIFT], 1);
    }
    __syncthreads();
    for (int t = threadIdx.x; t < nb; t += blockDim.x)
        if (lh[t]) atomicAdd(&hist[t], lh[t]);
}

// dinv[i] = rsqrt(cnt[i] + 1)   (+1 = self-loop)
__global__ void dinv_kernel(const int* __restrict__ cnt, float* __restrict__ dinv, int n) {
    int i = blockIdx.x * blockDim.x + threadIdx.x;
    if (i < n) dinv[i] = rsqrtf((float)cnt[i] + 1.0f);
}

// exclusive scan of hist -> segment starts (+ total at [nb]); init cursors
__global__ void scan_hist_kernel(const int* __restrict__ hist, int* __restrict__ segstart,
                                 int* __restrict__ gcur, int nb) {
    __shared__ int sh[NBMAX];
    int t = threadIdx.x;
    sh[t] = (t < nb) ? hist[t] : 0;
    __syncthreads();
    for (int d = 1; d < NBMAX; d <<= 1) {
        int v = (t >= d) ? sh[t - d] : 0;
        __syncthreads();
        sh[t] += v;
        __syncthreads();
    }
    int excl = (t == 0) ? 0 : sh[t - 1];
    if (t < nb) { segstart[t] = excl; gcur[t] = excl; }
    if (t == nb) segstart[nb] = sh[nb - 1];
}

// ---------------------------------------------------------------------------
// Binning: edge -> bucket segment of binned[], packed (src<<9)|dstLow.
// LDS-staged per bucket, flushed in 16-entry (64B) chunks -> full-line writes.
// ---------------------------------------------------------------------------
__global__ void bin_kernel(const int* __restrict__ src, const int* __restrict__ dst,
                           int* __restrict__ gcur, unsigned int* __restrict__ binned,
                           int E, int nb) {
    __shared__ unsigned int stage[NBMAX * CAP];   // 32 KB
    __shared__ int lcnt[NBMAX];
    for (int t = threadIdx.x; t < nb; t += blockDim.x) lcnt[t] = 0;
    __syncthreads();

    int per = (E + gridDim.x - 1) / gridDim.x;
    int s0 = blockIdx.x * per;
    int s1 = min(E, s0 + per);

    for (int base = s0; base < s1; base += blockDim.x) {
        int e = base + threadIdx.x;
        if (e < s1) {
            int s = src[e], d = dst[e];
            int b = d >> BSHIFT;
            unsigned int p = ((unsigned int)s << BSHIFT) | (unsigned int)(d & (BNODES - 1));
            int slot = atomicAdd(&lcnt[b], 1);
            if (slot < CAP) stage[b * CAP + slot] = p;
            else binned[atomicAdd(&gcur[b], 1)] = p;   // rare overflow
        }
        __syncthreads();
        int b = threadIdx.x;
        if (b < nb) {
            int c = lcnt[b];
            if (c > CAP) c = CAP;
            int nf = c & ~15;                           // full 16-entry chunks
            if (nf > 0) {
                int gp = atomicAdd(&gcur[b], nf);
                for (int k = 0; k < nf; ++k) binned[gp + k] = stage[b * CAP + k];
                for (int k = nf; k < c; ++k) stage[b * CAP + (k - nf)] = stage[b * CAP + k];
                lcnt[b] = c - nf;
            } else {
                lcnt[b] = c;                            // clamp after overflow
            }
        }
        __syncthreads();
    }
    // drain remainders
    int b = threadIdx.x;
    if (b < nb) {
        int c = lcnt[b];
        if (c > 0) {
            int gp = atomicAdd(&gcur[b], c);
            for (int k = 0; k < c; ++k) binned[gp + k] = stage[b * CAP + k];
        }
    }
}

// ---------------------------------------------------------------------------
// Y[n,16] = dinv[row] * (X[n,K] @ W[K,16])  — pre-scaled features
// ---------------------------------------------------------------------------
template <int K>
__global__ void gemm_kernel(const float* __restrict__ X, const float* __restrict__ W,
                            const float* __restrict__ dinv, float* __restrict__ Y, int n) {
    __shared__ float Wl[K * HDIM];
    for (int t = threadIdx.x; t < K * HDIM; t += blockDim.x) Wl[t] = W[t];
    __syncthreads();

    int row = blockIdx.x * blockDim.x + threadIdx.x;
    int stride = gridDim.x * blockDim.x;
    for (; row < n; row += stride) {
        float acc[HDIM];
#pragma unroll
        for (int j = 0; j < HDIM; ++j) acc[j] = 0.0f;
        const float* xr = X + (size_t)row * K;
#pragma unroll
        for (int k = 0; k < K; ++k) {
            float xv = xr[k];
#pragma unroll
            for (int j = 0; j < HDIM; ++j)
                acc[j] = fmaf(xv, Wl[k * HDIM + j], acc[j]);
        }
        float di = dinv[row];
        float4* yo = (float4*)(Y + (size_t)row * HDIM);
        yo[0] = make_float4(di * acc[0], di * acc[1], di * acc[2], di * acc[3]);
        yo[1] = make_float4(di * acc[4], di * acc[5], di * acc[6], di * acc[7]);
        yo[2] = make_float4(di * acc[8], di * acc[9], di * acc[10], di * acc[11]);
        yo[3] = make_float4(di * acc[12], di * acc[13], di * acc[14], di * acc[15]);
    }
}

// ---------------------------------------------------------------------------
// Aggregate one bucket part: LDS accum[512*16], stream edges, merge w/ atomics.
// target must be pre-zeroed. 16 threads per edge (j = tid&15).
// ---------------------------------------------------------------------------
__global__ void agg_kernel(const unsigned int* __restrict__ binned,
                           const int* __restrict__ segstart,
                           const float* __restrict__ hs, float* __restrict__ target, int n) {
    __shared__ float acc[BNODES * HDIM];   // 32 KB
    int bkt = blockIdx.x / SPLIT;
    int part = blockIdx.x % SPLIT;
    for (int t = threadIdx.x; t < BNODES * HDIM; t += blockDim.x) acc[t] = 0.0f;
    __syncthreads();

    int s = segstart[bkt];
    int len = segstart[bkt + 1] - s;
    int ps = s + (int)(((long long)len * part) / SPLIT);
    int pe = s + (int)(((long long)len * (part + 1)) / SPLIT);

    int j = threadIdx.x & 15;
    int eslot = threadIdx.x >> 4;          // 16 edges per iteration
#pragma unroll 4
    for (int e = ps + eslot; e < pe; e += 16) {
        unsigned int p = binned[e];
        int srcn = (int)(p >> BSHIFT);
        int dl = (int)(p & (BNODES - 1));
        atomicAdd(&acc[dl * HDIM + j], hs[(size_t)srcn * HDIM + j]);
    }
    __syncthreads();

    int nodeBase = bkt << BSHIFT;
    for (int t = threadIdx.x; t < BNODES * HDIM; t += blockDim.x) {
        int node = nodeBase + (t >> 4);
        if (node < n) {
            float v = acc[t];
            if (v != 0.0f) atomicAdd(&target[(size_t)node * HDIM + (t & 15)], v);
        }
    }
}

// ---------------------------------------------------------------------------
// finish: r = relu(dinv[i]*(acc[i,j] + hs[i,j]) + bias[j])
//   FUSE_W2: out[i,:] = dinv[i] * (r @ W2)   (pre-scaled for next layer)
//   else:    out[i,j] = r
// acc may alias out (thread-local idx, write after all reads/shuffles).
// ---------------------------------------------------------------------------
template <bool FUSE_W2>
__global__ void finish_kernel(const float* __restrict__ acc, const float* __restrict__ hs,
                              const float* __restrict__ dinv, const float* __restrict__ bias,
                              const float* __restrict__ W2, float* __restrict__ out, int n) {
    __shared__ float W2l[HDIM * HDIM];
    if constexpr (FUSE_W2) {
        for (int t = threadIdx.x; t < HDIM * HDIM; t += blockDim.x) W2l[t] = W2[t];
        __syncthreads();
    }
    int idx = blockIdx.x * blockDim.x + threadIdx.x;
    if (idx >= n * HDIM) return;
    int i = idx >> 4;
    int j = idx & 15;
    float di = dinv[i];
    float r = fmaxf(fmaf(di, acc[idx] + hs[idx], bias[j]), 0.0f);
    if constexpr (FUSE_W2) {
        float o = 0.0f;
#pragma unroll
        for (int jj = 0; jj < HDIM; ++jj) {
            float rv = __shfl(r, jj, HDIM);
            o = fmaf(rv, W2l[jj * HDIM + j], o);
        }
        out[idx] = di * o;
    } else {
        out[idx] = r;
    }
}

extern "C" void kernel_launch(void* const* d_in, const int* in_sizes, int n_in,
                              void* d_out, int out_size, void* d_ws, size_t ws_size,
                              hipStream_t stream) {
    const float* x  = (const float*)d_in[0];   // [n, 54]
    const int*   ei = (const int*)d_in[1];     // [2, E]
    const float* W1 = (const float*)d_in[2];   // [54, 16]
    const float* b1 = (const float*)d_in[3];   // [16]
    const float* W2 = (const float*)d_in[4];   // [16, 16]
    const float* b2 = (const float*)d_in[5];   // [16]
    float* out = (float*)d_out;

    const int E = in_sizes[1] / 2;             // 3,200,000
    const int n = in_sizes[0] / 54;            // 100,000
    const int* src = ei;
    const int* dst = ei + E;
    const int nb = (n + BNODES - 1) >> BSHIFT; // 196 buckets

    char* w = (char*)d_ws;
    float* dinv     = (float*)w;               w += (size_t)n * 4;
    float* hA       = (float*)w;               w += (size_t)n * HDIM * 4;
    float* hB       = (float*)w;               w += (size_t)n * HDIM * 4;
    int*   cnt      = (int*)w;                 w += (size_t)n * 4;
    int*   hist     = (int*)w;                 w += NBMAX * 4;   // contiguous with cnt
    int*   segstart = (int*)w;                 w += (NBMAX + 4) * 4;
    int*   gcur     = (int*)w;                 w += NBMAX * 4;
    unsigned int* binned = (unsigned int*)w;   // E u32

    const int B = 256;

    // --- build degree + bucket histogram + binned edge list (both layers) ---
    hipMemsetAsync(cnt, 0, ((size_t)n + NBMAX) * 4, stream);   // cnt + hist
    hist_count_kernel<<<1024, B, 0, stream>>>(dst, cnt, hist, E, nb);
    dinv_kernel<<<(n + B - 1) / B, B, 0, stream>>>(cnt, dinv, n);
    scan_hist_kernel<<<1, NBMAX, 0, stream>>>(hist, segstart, gcur, nb);
    bin_kernel<<<160, B, 0, stream>>>(src, dst, gcur, binned, E, nb);

    // --- layer 1 transform (pre-scaled by dinv) ---
    gemm_kernel<54><<<1024, B, 0, stream>>>(x, W1, dinv, hA, n);

    // --- layer 1 aggregate into hB, then relu + fused @W2 (pre-scaled) ---
    hipMemsetAsync(hB, 0, (size_t)n * HDIM * 4, stream);
    agg_kernel<<<nb * SPLIT, B, 0, stream>>>(binned, segstart, hA, hB, n);
    finish_kernel<true><<<(n * HDIM + B - 1) / B, B, 0, stream>>>(
        hB, hA, dinv, b1, W2, hB, n);

    // --- layer 2 aggregate into out, then bias + relu ---
    hipMemsetAsync(out, 0, (size_t)n * HDIM * 4, stream);
    agg_kernel<<<nb * SPLIT, B, 0, stream>>>(binned, segstart, hB, out, n);
    finish_kernel<false><<<(n * HDIM + B - 1) / B, B, 0, stream>>>(
        out, hB, dinv, b2, nullptr, out, n);
}

// Round 5
// 646.103 us; speedup vs baseline: 1.7709x; 1.7709x over previous
//
#include <hip/hip_runtime.h>

#define HDIM 16
#define BSHIFT 12                 // 4096 nodes per bucket
#define BNODES (1 << BSHIFT)
#define NBMAX 32                  // max buckets (n=100K -> 25)
#define NB_BLK 1024               // binning blocks == histogram columns
#define CMAP_SH 10                // 1024 edges per chunk in edge->bucket map

// ---------------------------------------------------------------------------
// pass 1: per-node degree (global atomics) + per-(bucket,block) histogram
// ---------------------------------------------------------------------------
__global__ void count_hist_kernel(const int* __restrict__ dst, int* __restrict__ cnt,
                                  int* __restrict__ gh, int E, int nb) {
    __shared__ int lh[NBMAX];
    if (threadIdx.x < NBMAX) lh[threadIdx.x] = 0;
    __syncthreads();
    int per = (E + NB_BLK - 1) / NB_BLK;
    int s0 = blockIdx.x * per;
    int s1 = min(E, s0 + per);
    for (int e = s0 + threadIdx.x; e < s1; e += blockDim.x) {
        int d = dst[e];
        atomicAdd(&cnt[d], 1);
        atomicAdd(&lh[d >> BSHIFT], 1);
    }
    __syncthreads();
    if (threadIdx.x < NBMAX)
        gh[threadIdx.x * NB_BLK + blockIdx.x] = lh[threadIdx.x];  // bucket-major
}

// dinv[i] = rsqrt(cnt[i] + 1)   (+1 = self-loop)
__global__ void dinv_kernel(const int* __restrict__ cnt, float* __restrict__ dinv, int n) {
    int i = blockIdx.x * blockDim.x + threadIdx.x;
    if (i < n) dinv[i] = rsqrtf((float)cnt[i] + 1.0f);
}

// ---------------------------------------------------------------------------
// generic exclusive scan (in place), 256 threads x 16 = 4096 elems per block
// ---------------------------------------------------------------------------
__global__ void scan1_kernel(int* __restrict__ data, int* __restrict__ bsum, int n) {
    __shared__ int sh[256];
    int off = blockIdx.x * 4096 + threadIdx.x * 16;
    int vals[16];
    int local = 0;
#pragma unroll
    for (int k = 0; k < 16; ++k) {
        int v = (off + k < n) ? data[off + k] : 0;
        vals[k] = v;
        local += v;
    }
    sh[threadIdx.x] = local;
    __syncthreads();
#pragma unroll
    for (int d = 1; d < 256; d <<= 1) {
        int t = (threadIdx.x >= d) ? sh[threadIdx.x - d] : 0;
        __syncthreads();
        sh[threadIdx.x] += t;
        __syncthreads();
    }
    int run = (threadIdx.x == 0) ? 0 : sh[threadIdx.x - 1];
#pragma unroll
    for (int k = 0; k < 16; ++k) {
        if (off + k < n) data[off + k] = run;
        run += vals[k];
    }
    if (threadIdx.x == 0) bsum[blockIdx.x] = sh[255];
}

__global__ void scan2_kernel(int* __restrict__ bsum, int nb) {
    __shared__ int sh[512];
    int v = (threadIdx.x < nb) ? bsum[threadIdx.x] : 0;
    sh[threadIdx.x] = v;
    __syncthreads();
    for (int d = 1; d < 512; d <<= 1) {
        int t = (threadIdx.x >= d) ? sh[threadIdx.x - d] : 0;
        __syncthreads();
        sh[threadIdx.x] += t;
        __syncthreads();
    }
    int excl = (threadIdx.x == 0) ? 0 : sh[threadIdx.x - 1];
    if (threadIdx.x < nb) bsum[threadIdx.x] = excl;
}

__global__ void scan3_kernel(int* __restrict__ data, const int* __restrict__ bsum, int n) {
    int i = blockIdx.x * blockDim.x + threadIdx.x;
    if (i < n) data[i] += bsum[i >> 12];
}

// ---------------------------------------------------------------------------
// segstart[b] = bucket start (b<=nb); cmap[m] = bucket containing edge m*1024
// ---------------------------------------------------------------------------
__global__ void segmap_kernel(const int* __restrict__ gh, int* __restrict__ segstart,
                              int* __restrict__ cmap, int nb, int nchunks, int E) {
    int t = blockIdx.x * blockDim.x + threadIdx.x;
    if (t <= nb) segstart[t] = (t == nb) ? E : gh[t * NB_BLK];
    if (t < nchunks) {
        int target = t << CMAP_SH;
        int lo = 0, hi = nb - 1;
        while (lo < hi) {
            int mid = (lo + hi + 1) >> 1;
            if (gh[mid * NB_BLK] <= target) lo = mid; else hi = mid - 1;
        }
        cmap[t] = lo;
    }
}

// ---------------------------------------------------------------------------
// pass 2: place edges at exact positions (LDS cursors from scanned gh)
// binned[pos] = (src<<12) | dstLow  -- per-(block,bucket) cells are contiguous
// ---------------------------------------------------------------------------
__global__ void fill_binned_kernel(const int* __restrict__ src, const int* __restrict__ dst,
                                   const int* __restrict__ gh, unsigned int* __restrict__ binned,
                                   int E, int nb) {
    __shared__ int lcur[NBMAX];
    if (threadIdx.x < NBMAX)
        lcur[threadIdx.x] = (threadIdx.x < nb) ? gh[threadIdx.x * NB_BLK + blockIdx.x] : 0;
    __syncthreads();
    int per = (E + NB_BLK - 1) / NB_BLK;
    int s0 = blockIdx.x * per;
    int s1 = min(E, s0 + per);
    for (int e = s0 + threadIdx.x; e < s1; e += blockDim.x) {
        int d = dst[e];
        int b = d >> BSHIFT;
        int pos = atomicAdd(&lcur[b], 1);
        binned[pos] = ((unsigned int)src[e] << BSHIFT) | (unsigned int)(d & (BNODES - 1));
    }
}

// ---------------------------------------------------------------------------
// Y[n,16] = dinv[row] * (X[n,K] @ W[K,16])  — pre-scaled features
// ---------------------------------------------------------------------------
template <int K>
__global__ void gemm_kernel(const float* __restrict__ X, const float* __restrict__ W,
                            const float* __restrict__ dinv, float* __restrict__ Y, int n) {
    __shared__ float Wl[K * HDIM];
    for (int t = threadIdx.x; t < K * HDIM; t += blockDim.x) Wl[t] = W[t];
    __syncthreads();

    int row = blockIdx.x * blockDim.x + threadIdx.x;
    int stride = gridDim.x * blockDim.x;
    for (; row < n; row += stride) {
        float acc[HDIM];
#pragma unroll
        for (int j = 0; j < HDIM; ++j) acc[j] = 0.0f;
        const float* xr = X + (size_t)row * K;
#pragma unroll
        for (int k = 0; k < K; ++k) {
            float xv = xr[k];
#pragma unroll
            for (int j = 0; j < HDIM; ++j)
                acc[j] = fmaf(xv, Wl[k * HDIM + j], acc[j]);
        }
        float di = dinv[row];
        float4* yo = (float4*)(Y + (size_t)row * HDIM);
        yo[0] = make_float4(di * acc[0], di * acc[1], di * acc[2], di * acc[3]);
        yo[1] = make_float4(di * acc[4], di * acc[5], di * acc[6], di * acc[7]);
        yo[2] = make_float4(di * acc[8], di * acc[9], di * acc[10], di * acc[11]);
        yo[3] = make_float4(di * acc[12], di * acc[13], di * acc[14], di * acc[15]);
    }
}

// ---------------------------------------------------------------------------
// flat scatter over bucket-sorted edges: agg[dst,:] += hs[src,:]
// 1 thread per (edge, feature); dst recovered via chunk map + <=1 fixup
// ---------------------------------------------------------------------------
__global__ void scatter_kernel(const unsigned int* __restrict__ binned,
                               const int* __restrict__ segstart, const int* __restrict__ cmap,
                               const float* __restrict__ hs, float* __restrict__ agg, int E) {
    int idx = blockIdx.x * blockDim.x + threadIdx.x;
    if (idx >= E * HDIM) return;
    int e = idx >> 4;
    int j = idx & 15;
    unsigned int p = binned[e];
    int bkt = cmap[e >> CMAP_SH];
    while (e >= segstart[bkt + 1]) ++bkt;
    int d = (bkt << BSHIFT) | (int)(p & (BNODES - 1));
    atomicAdd(&agg[(size_t)d * HDIM + j], hs[(size_t)(p >> BSHIFT) * HDIM + j]);
}

// ---------------------------------------------------------------------------
// finish: r = relu(dinv[i]*(acc[i,j] + hs[i,j]) + bias[j])
//   FUSE_W2: out[i,:] = dinv[i] * (r @ W2)   (pre-scaled for next layer)
// acc/hs/out may alias (idx-local; shuffles complete before the wave stores)
// ---------------------------------------------------------------------------
template <bool FUSE_W2>
__global__ void finish_kernel(const float* __restrict__ acc, const float* __restrict__ hs,
                              const float* __restrict__ dinv, const float* __restrict__ bias,
                              const float* __restrict__ W2, float* __restrict__ out, int n) {
    __shared__ float W2l[HDIM * HDIM];
    if constexpr (FUSE_W2) {
        for (int t = threadIdx.x; t < HDIM * HDIM; t += blockDim.x) W2l[t] = W2[t];
        __syncthreads();
    }
    int idx = blockIdx.x * blockDim.x + threadIdx.x;
    if (idx >= n * HDIM) return;
    int i = idx >> 4;
    int j = idx & 15;
    float di = dinv[i];
    float r = fmaxf(fmaf(di, acc[idx] + hs[idx], bias[j]), 0.0f);
    if constexpr (FUSE_W2) {
        float o = 0.0f;
#pragma unroll
        for (int jj = 0; jj < HDIM; ++jj) {
            float rv = __shfl(r, jj, HDIM);
            o = fmaf(rv, W2l[jj * HDIM + j], o);
        }
        out[idx] = di * o;
    } else {
        out[idx] = r;
    }
}

extern "C" void kernel_launch(void* const* d_in, const int* in_sizes, int n_in,
                              void* d_out, int out_size, void* d_ws, size_t ws_size,
                              hipStream_t stream) {
    const float* x  = (const float*)d_in[0];   // [n, 54]
    const int*   ei = (const int*)d_in[1];     // [2, E]
    const float* W1 = (const float*)d_in[2];   // [54, 16]
    const float* b1 = (const float*)d_in[3];   // [16]
    const float* W2 = (const float*)d_in[4];   // [16, 16]
    const float* b2 = (const float*)d_in[5];   // [16]
    float* out = (float*)d_out;

    const int E = in_sizes[1] / 2;             // 3,200,000
    const int n = in_sizes[0] / 54;            // 100,000
    const int* src = ei;
    const int* dst = ei + E;
    const int nb = (n + BNODES - 1) >> BSHIFT;          // 25 buckets
    const int nchunks = (E + (1 << CMAP_SH) - 1) >> CMAP_SH;  // 3125
    const int M2 = NBMAX * NB_BLK;                      // 32768 counters

    char* w = (char*)d_ws;
    float* dinv     = (float*)w;               w += (size_t)n * 4;
    float* hA       = (float*)w;               w += (size_t)n * HDIM * 4;
    float* agg      = (float*)w;               w += (size_t)n * HDIM * 4;
    int*   cnt      = (int*)w;                 w += (size_t)n * 4;
    int*   gh       = (int*)w;                 w += (size_t)M2 * 4;
    int*   bsum     = (int*)w;                 w += 512 * 4;
    int*   segstart = (int*)w;                 w += (NBMAX + 4) * 4;
    int*   cmap     = (int*)w;                 w += (size_t)nchunks * 4;
    unsigned int* binned = (unsigned int*)w;   // E u32  (~12.8 MB)

    const int B = 256;

    // --- build: degree + two-pass counting sort into bucket-sorted edges ---
    hipMemsetAsync(cnt, 0, (size_t)n * 4, stream);
    count_hist_kernel<<<NB_BLK, B, 0, stream>>>(dst, cnt, gh, E, nb);
    dinv_kernel<<<(n + B - 1) / B, B, 0, stream>>>(cnt, dinv, n);
    scan1_kernel<<<M2 / 4096, 256, 0, stream>>>(gh, bsum, M2);
    scan2_kernel<<<1, 512, 0, stream>>>(bsum, M2 / 4096);
    scan3_kernel<<<M2 / B, B, 0, stream>>>(gh, bsum, M2);
    segmap_kernel<<<(nchunks + B - 1) / B, B, 0, stream>>>(gh, segstart, cmap, nb, nchunks, E);
    fill_binned_kernel<<<NB_BLK, B, 0, stream>>>(src, dst, gh, binned, E, nb);

    // --- layer 1 transform (pre-scaled by dinv) ---
    gemm_kernel<54><<<1024, B, 0, stream>>>(x, W1, dinv, hA, n);

    // --- layer 1 aggregate + relu + fused @W2 (pre-scaled), in place ---
    hipMemsetAsync(agg, 0, (size_t)n * HDIM * 4, stream);
    scatter_kernel<<<(E * HDIM + B - 1) / B, B, 0, stream>>>(binned, segstart, cmap, hA, agg, E);
    finish_kernel<true><<<(n * HDIM + B - 1) / B, B, 0, stream>>>(agg, hA, dinv, b1, W2, agg, n);

    // --- layer 2 aggregate + bias + relu -> out ---
    hipMemsetAsync(hA, 0, (size_t)n * HDIM * 4, stream);
    scatter_kernel<<<(E * HDIM + B - 1) / B, B, 0, stream>>>(binned, segstart, cmap, agg, hA, E);
    finish_kernel<false><<<(n * HDIM + B - 1) / B, B, 0, stream>>>(hA, agg, dinv, b2, nullptr, out, n);
}